// Round 1
// baseline (1912.413 us; speedup 1.0000x reference)
//
#include <hip/hip_runtime.h>

// Problem constants
#define NB 8      // batch
#define TT 1024   // Tq = Tk
#define DD 512    // input dim
#define UU 512    // projected dim
#define HH 8      // heads
#define DH 64     // head dim
#define SCALE 0.044194173824159216f  // 1/sqrt(512)
#define MASK_FILL -1000000.0f

// ---------- flexible dtype load (fp32 or bf16, decided by device flag) ----------
__device__ __forceinline__ float ld_flex(const void* p, long i, bool f32) {
  if (f32) return ((const float*)p)[i];
  unsigned int u = (unsigned int)(((const unsigned short*)p)[i]) << 16;
  return __uint_as_float(u);
}

__device__ __forceinline__ unsigned short f32_to_bf16(float f) {
  unsigned int u = __float_as_uint(f);
  unsigned int r = (u + 0x7FFFu + ((u >> 16) & 1u)) >> 16;  // RNE
  return (unsigned short)r;
}

// ---------- probe: decide float dtype (fp32 vs bf16) and mask layout ----------
// flags[0] = 1 if float inputs are fp32, 0 if bf16
// flags[1] = 1 if mask is int32, 0 if byte
__global__ void probe_kernel(const void* __restrict__ qptr,
                             const void* __restrict__ mptr,
                             int* __restrict__ flags) {
  __shared__ int s_f32, s_mi32;
  if (threadIdx.x == 0) { s_f32 = 0; s_mi32 = 1; }
  __syncthreads();
  // Read first 4096 elements of query as bf16 (8 KB; buffer is >=16 KB under
  // either interpretation). Real bf16 data ~N(0,1): all small/finite. fp32 data
  // read as bf16 stream: low halves decode to garbage exponents -> huge/NaN.
  const unsigned short* qh = (const unsigned short*)qptr;
  int weird = 0;
  for (int i = threadIdx.x; i < 4096; i += 256) {
    unsigned int u = (unsigned int)qh[i] << 16;
    float v = __uint_as_float(u);
    if (!(v == v) || fabsf(v) > 1e6f) weird = 1;
  }
  if (weird) atomicOr(&s_f32, 1);
  // Mask: 8192 bool elements. As int32 they are {0,1}. As packed bytes, a u32
  // word of 4 random 0/1 bytes exceeds 1 with prob ~15/16 per word.
  const unsigned int* mi = (const unsigned int*)mptr;
  int bad = 0;
  for (int i = threadIdx.x; i < 2048; i += 256) {
    if (mi[i] > 1u) bad = 1;
  }
  if (bad) atomicAnd(&s_mi32, 0);
  __syncthreads();
  if (threadIdx.x == 0) { flags[0] = s_f32; flags[1] = s_mi32; }
}

// ---------- projection GEMM: C[M=8192, 512] = A[8192,512] @ B[512,512] ----------
#define GBM 64
#define GBN 64
#define GBK 16

__global__ __launch_bounds__(256) void proj_gemm(
    const void* __restrict__ A, const void* __restrict__ B,
    float* __restrict__ C, const int* __restrict__ flags) {
  const int K = DD, Nn = UU;
  __shared__ float As[GBK][GBM + 1];              // +1 pad: conflict-free writes
  __shared__ __align__(16) float Bs[GBK][GBN];
  const int bm = blockIdx.y * GBM, bn = blockIdx.x * GBN;
  const int tid = threadIdx.x;
  const int tm = (tid >> 4) << 2;
  const int tn = (tid & 15) << 2;
  const bool f32 = flags[0] != 0;
  float acc[4][4] = {};
  for (int k0 = 0; k0 < K; k0 += GBK) {
    for (int i = tid; i < GBM * GBK; i += 256) {
      int m = i >> 4, kk = i & 15;
      As[kk][m] = ld_flex(A, (long)(bm + m) * K + k0 + kk, f32);
    }
    for (int i = tid; i < GBK * GBN; i += 256) {
      int kk = i >> 6, nn = i & 63;
      Bs[kk][nn] = ld_flex(B, (long)(k0 + kk) * Nn + bn + nn, f32);
    }
    __syncthreads();
#pragma unroll
    for (int kk = 0; kk < GBK; ++kk) {
      float a[4];
#pragma unroll
      for (int x = 0; x < 4; ++x) a[x] = As[kk][tm + x];   // broadcast reads
      float4 b = *(const float4*)&Bs[kk][tn];              // conflict-free b128
#pragma unroll
      for (int x = 0; x < 4; ++x) {
        acc[x][0] += a[x] * b.x;
        acc[x][1] += a[x] * b.y;
        acc[x][2] += a[x] * b.z;
        acc[x][3] += a[x] * b.w;
      }
    }
    __syncthreads();
  }
#pragma unroll
  for (int x = 0; x < 4; ++x) {
    float4 o = make_float4(acc[x][0], acc[x][1], acc[x][2], acc[x][3]);
    *(float4*)&C[(long)(bm + tm + x) * Nn + bn + tn] = o;
  }
}

// ---------- attention: one block per (n, h, 8 query rows) ----------
#define QB 8

__global__ __launch_bounds__(256) void attn_kernel(
    const float* __restrict__ Q, const float* __restrict__ K,
    const float* __restrict__ V, const void* __restrict__ maskp,
    void* __restrict__ out, const int* __restrict__ flags) {
  __shared__ float qs[QB][DH];       // 2 KB
  __shared__ float sc[QB][TT];       // 32 KB
  __shared__ float inv_s[QB];
  __shared__ float part[4][QB][DH];  // 8 KB
  const int qb = blockIdx.x;   // 0..127
  const int h  = blockIdx.y;   // 0..7
  const int n  = blockIdx.z;   // 0..7
  const int tid = threadIdx.x;
  const int q0 = qb * QB;
  const bool f32 = flags[0] != 0;
  const bool mask_i32 = flags[1] != 0;
  const int* mi = (const int*)maskp;
  const unsigned char* mb = (const unsigned char*)maskp;

  for (int i = tid; i < QB * DH; i += 256) {
    int r = i >> 6, j = i & 63;
    qs[r][j] = Q[((long)(n * TT) + q0 + r) * UU + h * DH + j];
  }
  __syncthreads();

  // ---- scores: each thread handles 4 keys (2 per pass, q-reads shared) ----
  for (int kk = 0; kk < TT; kk += 512) {
    const int k0 = kk + tid;
    const int k1 = k0 + 256;
    const float* kr0 = K + ((long)(n * TT) + k0) * UU + h * DH;
    const float* kr1 = K + ((long)(n * TT) + k1) * UU + h * DH;
    float a0[QB] = {}, a1[QB] = {};
#pragma unroll
    for (int i = 0; i < DH; i += 4) {
      float4 x0 = *(const float4*)(kr0 + i);
      float4 x1 = *(const float4*)(kr1 + i);
#pragma unroll
      for (int r = 0; r < QB; ++r) {
        float q0v = qs[r][i], q1v = qs[r][i + 1], q2v = qs[r][i + 2], q3v = qs[r][i + 3];
        a0[r] += q0v * x0.x + q1v * x0.y + q2v * x0.z + q3v * x0.w;
        a1[r] += q0v * x1.x + q1v * x1.y + q2v * x1.z + q3v * x1.w;
      }
    }
    const bool m0 = mask_i32 ? (mi[n * TT + k0] != 0) : (mb[n * TT + k0] != 0);
    const bool m1 = mask_i32 ? (mi[n * TT + k1] != 0) : (mb[n * TT + k1] != 0);
#pragma unroll
    for (int r = 0; r < QB; ++r) {
      sc[r][k0] = m0 ? a0[r] * SCALE : MASK_FILL;
      sc[r][k1] = m1 ? a1[r] * SCALE : MASK_FILL;
    }
  }
  __syncthreads();

  // ---- softmax: 8 groups of 32 lanes, one row each ----
  {
    const int r = tid >> 5, lane = tid & 31;
    float pm = -INFINITY;
    for (int k = lane; k < TT; k += 32) pm = fmaxf(pm, sc[r][k]);
#pragma unroll
    for (int d = 16; d > 0; d >>= 1) pm = fmaxf(pm, __shfl_down(pm, d, 32));
    pm = __shfl(pm, 0, 32);
    float ps = 0.f;
    for (int k = lane; k < TT; k += 32) {
      float p = __expf(sc[r][k] - pm);
      sc[r][k] = p;
      ps += p;
    }
#pragma unroll
    for (int d = 16; d > 0; d >>= 1) ps += __shfl_down(ps, d, 32);
    if (lane == 0) inv_s[r] = 1.0f / ps;
  }
  __syncthreads();

  // ---- PV: 4 k-groups x 64 output dims, each V element read once ----
  {
    const int j = tid & 63, kg = tid >> 6;
    float acc[QB] = {};
    const float* vbase = V + (long)(n * TT) * UU + h * DH + j;
    for (int k = kg * 256; k < kg * 256 + 256; ++k) {
      float vv = vbase[(long)k * UU];
#pragma unroll
      for (int r = 0; r < QB; ++r) acc[r] += sc[r][k] * vv;
    }
#pragma unroll
    for (int r = 0; r < QB; ++r) part[kg][r][j] = acc[r];
  }
  __syncthreads();

  for (int i = tid; i < QB * DH; i += 256) {
    int r = i >> 6, j = i & 63;
    float o = (part[0][r][j] + part[1][r][j] + part[2][r][j] + part[3][r][j]) * inv_s[r];
    long oi = ((long)(n * TT) + q0 + r) * UU + h * DH + j;
    if (f32) ((float*)out)[oi] = o;
    else ((unsigned short*)out)[oi] = f32_to_bf16(o);
  }
}

// ---------- launcher ----------
extern "C" void kernel_launch(void* const* d_in, const int* in_sizes, int n_in,
                              void* d_out, int out_size, void* d_ws, size_t ws_size,
                              hipStream_t stream) {
  const void* query = d_in[0];
  const void* key   = d_in[1];
  const void* mask  = d_in[2];
  const void* Wq    = d_in[3];
  const void* Wk    = d_in[4];
  const void* Wv    = d_in[5];

  int* flags = (int*)d_ws;
  float* Qf = (float*)((char*)d_ws + 256);
  float* Kf = Qf + (long)NB * TT * UU;
  float* Vf = Kf + (long)NB * TT * UU;

  probe_kernel<<<1, 256, 0, stream>>>(query, mask, flags);

  dim3 ggrid(UU / GBN, (NB * TT) / GBM);  // (8, 128)
  proj_gemm<<<ggrid, 256, 0, stream>>>(query, Wq, Qf, flags);
  proj_gemm<<<ggrid, 256, 0, stream>>>(key,   Wk, Kf, flags);
  proj_gemm<<<ggrid, 256, 0, stream>>>(key,   Wv, Vf, flags);

  dim3 agrid(TT / QB, HH, NB);  // (128, 8, 8)
  attn_kernel<<<agrid, 256, 0, stream>>>(Qf, Kf, Vf, mask, d_out, flags);
}

// Round 2
// 262.863 us; speedup vs baseline: 7.2753x; 7.2753x over previous
//
#include <hip/hip_runtime.h>

typedef unsigned short u16;
typedef __attribute__((ext_vector_type(8))) short short8;
typedef __attribute__((ext_vector_type(4))) float f32x4;

#define NB 8
#define TT 1024
#define DD 512
#define UU 512
#define HH 8
#define DH 64
#define SCALE 0.044194173824159216f  // 1/sqrt(512)
#define MASK_FILL -1000000.0f

__device__ __forceinline__ float ld_flex(const void* p, long i, bool f32) {
  if (f32) return ((const float*)p)[i];
  unsigned int u = (unsigned int)(((const u16*)p)[i]) << 16;
  return __uint_as_float(u);
}

__device__ __forceinline__ u16 f32_to_bf16(float f) {
  unsigned int u = __float_as_uint(f);
  unsigned int r = (u + 0x7FFFu + ((u >> 16) & 1u)) >> 16;  // RNE
  return (u16)r;
}

// ---------- probe: input dtype + mask layout; also build maskadd ----------
__global__ void probe_kernel(const void* __restrict__ qptr,
                             const void* __restrict__ mptr,
                             int* __restrict__ flags,
                             float* __restrict__ maskadd) {
  __shared__ int s_f32, s_mi32;
  if (threadIdx.x == 0) { s_f32 = 0; s_mi32 = 1; }
  __syncthreads();
  const u16* qh = (const u16*)qptr;
  int weird = 0;
  for (int i = threadIdx.x; i < 4096; i += 256) {
    unsigned int u = (unsigned int)qh[i] << 16;
    float v = __uint_as_float(u);
    if (!(v == v) || fabsf(v) > 1e6f) weird = 1;
  }
  if (weird) atomicOr(&s_f32, 1);
  const unsigned int* mi = (const unsigned int*)mptr;
  int bad = 0;
  for (int i = threadIdx.x; i < 2048; i += 256) {
    if (mi[i] > 1u) bad = 1;
  }
  if (bad) atomicAnd(&s_mi32, 0);
  __syncthreads();
  if (threadIdx.x == 0) { flags[0] = s_f32; flags[1] = s_mi32; }
  const bool mi32 = (s_mi32 != 0);
  const int* mw = (const int*)mptr;
  const unsigned char* mb = (const unsigned char*)mptr;
  for (int i = threadIdx.x; i < NB * TT; i += 256) {
    bool mv = mi32 ? (mw[i] != 0) : (mb[i] != 0);
    maskadd[i] = mv ? 0.0f : MASK_FILL;
  }
}

// ---------- convert fp32/bf16 input -> bf16, 4 elems/thread ----------
__global__ __launch_bounds__(256) void convert_bf16(
    const void* __restrict__ in, u16* __restrict__ out, int n4,
    const int* __restrict__ flags) {
  const bool f32 = flags[0] != 0;
  int i = blockIdx.x * 256 + threadIdx.x;
  if (i >= n4) return;
  ushort4 o;
  if (f32) {
    float4 v = ((const float4*)in)[i];
    o.x = f32_to_bf16(v.x); o.y = f32_to_bf16(v.y);
    o.z = f32_to_bf16(v.z); o.w = f32_to_bf16(v.w);
  } else {
    o = ((const ushort4*)in)[i];
  }
  ((ushort4*)out)[i] = o;
}

// ---------- weight transpose: Wt[n][k] = W[k][n], bf16 ----------
__global__ __launch_bounds__(256) void wtrans(
    const void* __restrict__ W0, const void* __restrict__ W1,
    const void* __restrict__ W2, u16* __restrict__ Wt,
    const int* __restrict__ flags) {
  const bool f32 = flags[0] != 0;
  const void* W = (blockIdx.z == 0) ? W0 : (blockIdx.z == 1) ? W1 : W2;
  u16* out = Wt + (size_t)blockIdx.z * DD * UU;
  __shared__ float tile[32][33];
  const int k0 = blockIdx.x * 32, n0 = blockIdx.y * 32;
  const int tid = threadIdx.x;
#pragma unroll
  for (int p = 0; p < 4; ++p) {
    int i = (tid >> 5) + p * 8, j = tid & 31;
    tile[i][j] = ld_flex(W, (long)(k0 + i) * UU + n0 + j, f32);
  }
  __syncthreads();
#pragma unroll
  for (int p = 0; p < 4; ++p) {
    int nl = (tid >> 5) + p * 8, kl = tid & 31;
    out[(size_t)(n0 + nl) * DD + k0 + kl] = f32_to_bf16(tile[kl][nl]);
  }
}

// ---------- MFMA projection: C[8192x512] = X[8192x512] @ W, W given transposed ----------
// One wave per block; wave computes 32(m) x 64(n). vmode 0: row-major bf16 out.
// vmode 1: transposed per-head out Vt[(nb*8+h)*64+dh][1024tk].
__global__ __launch_bounds__(64) void proj_mfma(
    const u16* __restrict__ X, const u16* __restrict__ Wt,
    u16* __restrict__ out, int vmode) {
  const int l = threadIdx.x, quad = l >> 4, l15 = l & 15;
  const int m0 = blockIdx.x * 32, n0 = blockIdx.y * 64;
  const u16* abase = X + (size_t)(m0 + l15) * DD + quad * 8;
  const u16* bbase = Wt + (size_t)(n0 + l15) * DD + quad * 8;

  short8 ac[2], bc[4], an[2], bn[4];
  ac[0] = *(const short8*)(abase);
  ac[1] = *(const short8*)(abase + 16 * DD);
#pragma unroll
  for (int ni = 0; ni < 4; ++ni) bc[ni] = *(const short8*)(bbase + ni * 16 * DD);

  f32x4 acc[2][4];
#pragma unroll
  for (int qi = 0; qi < 2; ++qi)
#pragma unroll
    for (int ni = 0; ni < 4; ++ni)
#pragma unroll
      for (int r = 0; r < 4; ++r) acc[qi][ni][r] = 0.0f;

  for (int k0 = 0; k0 < DD; k0 += 32) {
    const int k2 = (k0 + 32) & (DD - 1);
    an[0] = *(const short8*)(abase + k2);
    an[1] = *(const short8*)(abase + 16 * DD + k2);
#pragma unroll
    for (int ni = 0; ni < 4; ++ni)
      bn[ni] = *(const short8*)(bbase + ni * 16 * DD + k2);
#pragma unroll
    for (int qi = 0; qi < 2; ++qi)
#pragma unroll
      for (int ni = 0; ni < 4; ++ni)
        acc[qi][ni] = __builtin_amdgcn_mfma_f32_16x16x32_bf16(
            ac[qi], bc[ni], acc[qi][ni], 0, 0, 0);
    ac[0] = an[0]; ac[1] = an[1];
#pragma unroll
    for (int ni = 0; ni < 4; ++ni) bc[ni] = bn[ni];
  }

  if (vmode == 0) {
#pragma unroll
    for (int qi = 0; qi < 2; ++qi)
#pragma unroll
      for (int ni = 0; ni < 4; ++ni)
#pragma unroll
        for (int r = 0; r < 4; ++r) {
          int m = m0 + qi * 16 + quad * 4 + r;
          int u = n0 + ni * 16 + l15;
          out[(size_t)m * UU + u] = f32_to_bf16(acc[qi][ni][r]);
        }
  } else {
#pragma unroll
    for (int qi = 0; qi < 2; ++qi)
#pragma unroll
      for (int ni = 0; ni < 4; ++ni) {
        int m = m0 + qi * 16 + quad * 4;  // tk base (r consecutive)
        int nb = m >> 10, tk = m & 1023;
        int u = n0 + ni * 16 + l15;
        int h = u >> 6, dh = u & 63;
        ushort4 pk;
        pk.x = f32_to_bf16(acc[qi][ni][0]);
        pk.y = f32_to_bf16(acc[qi][ni][1]);
        pk.z = f32_to_bf16(acc[qi][ni][2]);
        pk.w = f32_to_bf16(acc[qi][ni][3]);
        *(ushort4*)&out[(size_t)((nb * HH + h) * DH + dh) * TT + tk] = pk;
      }
  }
}

// ---------- flash attention: 1 wave per (n, h, 32-query tile) ----------
__global__ __launch_bounds__(64) void attn_mfma(
    const u16* __restrict__ Qp, const u16* __restrict__ Kp,
    const u16* __restrict__ Vt, const float* __restrict__ maskadd,
    void* __restrict__ out, const int* __restrict__ flags) {
  __shared__ u16 Pbuf[32][40];  // 32q x 32k, +8 pad (row 80B)
  const int l = threadIdx.x;
  const int quad = l >> 4, l15 = l & 15;
  const int qt = blockIdx.x, h = blockIdx.y, n = blockIdx.z;
  const int q0 = qt * 32;
  const bool f32o = flags[0] != 0;

  // Q A-frags (resident): aq[qi][kd], q = q0+qi*16+l15, d = kd*32+quad*8+j
  const u16* qbase = Qp + (size_t)(n * TT + q0 + l15) * UU + h * DH + quad * 8;
  short8 aq[2][2];
  aq[0][0] = *(const short8*)(qbase);
  aq[0][1] = *(const short8*)(qbase + 32);
  aq[1][0] = *(const short8*)(qbase + 16 * UU);
  aq[1][1] = *(const short8*)(qbase + 16 * UU + 32);

  const u16* kbase = Kp + (size_t)(n * TT + l15) * UU + h * DH + quad * 8;
  const u16* vbase = Vt + (size_t)((n * HH + h) * DH + l15) * TT + quad * 8;
  const float* mbase = maskadd + n * TT + l15;

  f32x4 o[2][4];
  float mrow[2][4], lrow[2][4];
#pragma unroll
  for (int qi = 0; qi < 2; ++qi)
#pragma unroll
    for (int r = 0; r < 4; ++r) { mrow[qi][r] = -3e38f; lrow[qi][r] = 0.0f; }
#pragma unroll
  for (int qi = 0; qi < 2; ++qi)
#pragma unroll
    for (int ni = 0; ni < 4; ++ni)
#pragma unroll
      for (int r = 0; r < 4; ++r) o[qi][ni][r] = 0.0f;

  // K B-frags: kf[ki][kd], key = kb+ki*16+l15, d = kd*32+quad*8+j
  short8 kf[2][2], kn[2][2];
#pragma unroll
  for (int ki = 0; ki < 2; ++ki)
#pragma unroll
    for (int kd = 0; kd < 2; ++kd)
      kf[ki][kd] = *(const short8*)(kbase + (size_t)(ki * 16) * UU + kd * 32);

  for (int kb = 0; kb < TT; kb += 32) {
    // V B-frags for current tile: vf[ni], dh = ni*16+l15, key = kb+quad*8+j
    short8 vf[4];
#pragma unroll
    for (int ni = 0; ni < 4; ++ni)
      vf[ni] = *(const short8*)(vbase + (size_t)(ni * 16) * TT + kb);
    const float mk0 = mbase[kb];
    const float mk1 = mbase[kb + 16];
    // prefetch next K tile
    const int kb2 = (kb + 32) & (TT - 1);
#pragma unroll
    for (int ki = 0; ki < 2; ++ki)
#pragma unroll
      for (int kd = 0; kd < 2; ++kd)
        kn[ki][kd] = *(const short8*)(kbase + (size_t)(kb2 + ki * 16) * UU + kd * 32);

    // S = Q K^T  (32q x 32k)
    f32x4 s[2][2];
#pragma unroll
    for (int qi = 0; qi < 2; ++qi)
#pragma unroll
      for (int ki = 0; ki < 2; ++ki) {
#pragma unroll
        for (int r = 0; r < 4; ++r) s[qi][ki][r] = 0.0f;
#pragma unroll
        for (int kd = 0; kd < 2; ++kd)
          s[qi][ki] = __builtin_amdgcn_mfma_f32_16x16x32_bf16(
              aq[qi][kd], kf[ki][kd], s[qi][ki], 0, 0, 0);
      }

    // online softmax, P -> LDS (bf16, A-layout via round-trip)
#pragma unroll
    for (int qi = 0; qi < 2; ++qi) {
      float p0[4], p1[4], t[4];
#pragma unroll
      for (int r = 0; r < 4; ++r) {
        p0[r] = s[qi][0][r] * SCALE + mk0;
        p1[r] = s[qi][1][r] * SCALE + mk1;
        t[r] = fmaxf(p0[r], p1[r]);
      }
#pragma unroll
      for (int m = 1; m <= 8; m <<= 1)
#pragma unroll
        for (int r = 0; r < 4; ++r) t[r] = fmaxf(t[r], __shfl_xor(t[r], m));
      float alpha[4];
#pragma unroll
      for (int r = 0; r < 4; ++r) {
        float mn = fmaxf(mrow[qi][r], t[r]);
        alpha[r] = __expf(mrow[qi][r] - mn);
        mrow[qi][r] = mn;
      }
      float u[4];
#pragma unroll
      for (int r = 0; r < 4; ++r) {
        p0[r] = __expf(p0[r] - mrow[qi][r]);
        p1[r] = __expf(p1[r] - mrow[qi][r]);
        u[r] = p0[r] + p1[r];
      }
#pragma unroll
      for (int m = 1; m <= 8; m <<= 1)
#pragma unroll
        for (int r = 0; r < 4; ++r) u[r] += __shfl_xor(u[r], m);
#pragma unroll
      for (int r = 0; r < 4; ++r)
        lrow[qi][r] = lrow[qi][r] * alpha[r] + u[r];
#pragma unroll
      for (int ni = 0; ni < 4; ++ni)
#pragma unroll
        for (int r = 0; r < 4; ++r) o[qi][ni][r] *= alpha[r];
#pragma unroll
      for (int r = 0; r < 4; ++r) {
        Pbuf[qi * 16 + quad * 4 + r][l15] = f32_to_bf16(p0[r]);
        Pbuf[qi * 16 + quad * 4 + r][16 + l15] = f32_to_bf16(p1[r]);
      }
    }

    // P A-frags: q = qi*16+l15, key = quad*8+j
    short8 ap0 = *(const short8*)&Pbuf[l15][quad * 8];
    short8 ap1 = *(const short8*)&Pbuf[16 + l15][quad * 8];
    // O += P V
#pragma unroll
    for (int ni = 0; ni < 4; ++ni) {
      o[0][ni] = __builtin_amdgcn_mfma_f32_16x16x32_bf16(ap0, vf[ni], o[0][ni], 0, 0, 0);
      o[1][ni] = __builtin_amdgcn_mfma_f32_16x16x32_bf16(ap1, vf[ni], o[1][ni], 0, 0, 0);
    }
    // rotate K prefetch
#pragma unroll
    for (int ki = 0; ki < 2; ++ki)
#pragma unroll
      for (int kd = 0; kd < 2; ++kd) kf[ki][kd] = kn[ki][kd];
  }

  // normalize + store
#pragma unroll
  for (int qi = 0; qi < 2; ++qi) {
    float inv[4];
#pragma unroll
    for (int r = 0; r < 4; ++r) inv[r] = 1.0f / lrow[qi][r];
#pragma unroll
    for (int ni = 0; ni < 4; ++ni)
#pragma unroll
      for (int r = 0; r < 4; ++r) {
        float v = o[qi][ni][r] * inv[r];
        int row = q0 + qi * 16 + quad * 4 + r;
        size_t idx = (size_t)(n * TT + row) * UU + h * DH + ni * 16 + l15;
        if (f32o) ((float*)out)[idx] = v;
        else ((u16*)out)[idx] = f32_to_bf16(v);
      }
  }
}

// ---------- launcher ----------
extern "C" void kernel_launch(void* const* d_in, const int* in_sizes, int n_in,
                              void* d_out, int out_size, void* d_ws, size_t ws_size,
                              hipStream_t stream) {
  const void* query = d_in[0];
  const void* key   = d_in[1];
  const void* mask  = d_in[2];
  const void* Wq    = d_in[3];
  const void* Wk    = d_in[4];
  const void* Wv    = d_in[5];

  char* base = (char*)d_ws;
  int* flags = (int*)base;
  float* maskadd = (float*)(base + 256);                  // 32 KB
  u16* Xq = (u16*)(base + 64 * 1024);                     // 8 MB
  u16* Xk = Xq + (size_t)NB * TT * DD;                    // 8 MB
  u16* Wt = Xk + (size_t)NB * TT * DD;                    // 1.5 MB
  u16* Qp = Wt + (size_t)3 * DD * UU;                     // 8 MB
  u16* Kp = Qp + (size_t)NB * TT * UU;                    // 8 MB
  u16* Vtp = Kp + (size_t)NB * TT * UU;                   // 8 MB

  probe_kernel<<<1, 256, 0, stream>>>(query, mask, flags, maskadd);

  const int n4 = NB * TT * DD / 4;  // 1M vec4 elems
  convert_bf16<<<(n4 + 255) / 256, 256, 0, stream>>>(query, Xq, n4, flags);
  convert_bf16<<<(n4 + 255) / 256, 256, 0, stream>>>(key, Xk, n4, flags);

  wtrans<<<dim3(16, 16, 3), 256, 0, stream>>>(Wq, Wk, Wv, Wt, flags);

  dim3 pgrid(NB * TT / 32, UU / 64);  // (256, 8)
  proj_mfma<<<pgrid, 64, 0, stream>>>(Xq, Wt, Qp, 0);
  proj_mfma<<<pgrid, 64, 0, stream>>>(Xk, Wt + (size_t)DD * UU, Kp, 0);
  proj_mfma<<<pgrid, 64, 0, stream>>>(Xk, Wt + (size_t)2 * DD * UU, Vtp, 1);

  dim3 agrid(TT / 32, HH, NB);  // (32, 8, 8)
  attn_mfma<<<agrid, 64, 0, stream>>>(Qp, Kp, Vtp, maskadd, d_out, flags);
}